// Round 6
// baseline (106.144 us; speedup 1.0000x reference)
//
#include <hip/hip_runtime.h>
#include <math.h>

// Problem constants
#define BB 64
#define QQ 100
#define NN 16
#define CC 2048            // NUM_CLASSES + 1
#define TIME_WEIGHT 2.0f
#define EOS_COEF 0.1f

__device__ __forceinline__ double readlane_d(double x, int lane) {
    int lo = __builtin_amdgcn_readlane(__double2loint(x), lane);
    int hi = __builtin_amdgcn_readlane(__double2hiint(x), lane);
    return __hiloint2double(hi, lo);
}

__device__ __forceinline__ float readlane_f(float x, int lane) {
    return __int_as_float(__builtin_amdgcn_readlane(__float_as_int(x), lane));
}

// fmin/fmax with a DPP-permuted copy of x (32-bit halves moved coherently).
// old = src => lanes not written by the DPP pattern keep their own value,
// which is a no-op for min/max. Used patterns: quad_perm xor1 (0xB1),
// quad_perm xor2 (0x4E), row_ror:4 (0x124), row_ror:8 (0x128),
// row_bcast15 (0x142: lanes 16-31<-15, 48-63<-47),
// row_bcast31 (0x143: lanes 32-63<-31).
template <int CTRL>
__device__ __forceinline__ double dpp_fmin_f64(double x) {
    int lo_s = __double2loint(x), hi_s = __double2hiint(x);
    int lo = __builtin_amdgcn_update_dpp(lo_s, lo_s, CTRL, 0xF, 0xF, false);
    int hi = __builtin_amdgcn_update_dpp(hi_s, hi_s, CTRL, 0xF, 0xF, false);
    return fmin(x, __hiloint2double(hi, lo));
}
template <int CTRL>
__device__ __forceinline__ float dpp_fmax_f32(float x) {
    int xi = __float_as_int(x);
    int yi = __builtin_amdgcn_update_dpp(xi, xi, CTRL, 0xF, 0xF, false);
    return fmaxf(x, __int_as_float(yi));
}

// Keep all 8 float4 row chunks live in VGPRs (32 regs). Without this the
// compiler allocates only 28 VGPRs total (measured R0-R4) and serializes the
// 8 independent dwordx4 loads into a few-in-flight chunked pattern --
// latency-starving the streaming pass. Zero instructions emitted.
#define KEEP_ALIVE_V8(v)                                                     \
    asm volatile("" : "+v"(v[0].x), "+v"(v[0].y), "+v"(v[0].z), "+v"(v[0].w),\
                     "+v"(v[1].x), "+v"(v[1].y), "+v"(v[1].z), "+v"(v[1].w),\
                     "+v"(v[2].x), "+v"(v[2].y), "+v"(v[2].z), "+v"(v[2].w),\
                     "+v"(v[3].x), "+v"(v[3].y), "+v"(v[3].z), "+v"(v[3].w));\
    asm volatile("" : "+v"(v[4].x), "+v"(v[4].y), "+v"(v[4].z), "+v"(v[4].w),\
                     "+v"(v[5].x), "+v"(v[5].y), "+v"(v[5].z), "+v"(v[5].w),\
                     "+v"(v[6].x), "+v"(v[6].y), "+v"(v[6].z), "+v"(v[6].w),\
                     "+v"(v[7].x), "+v"(v[7].y), "+v"(v[7].z), "+v"(v[7].w))

// ---------------------------------------------------------------------------
// Kernel 1: per (b,q) row (one wave each):
//   logZ[b,q] = logsumexp(logits[b,q,:])
//   Cg[b][n][q] = -softmax[label_n] + 2*|pt - ts_n|   (transposed cost matrix)
//   lsepart[block] = sum over 4 rows of (logZ - logit[class 0])   [EOS nll]
// Block 0 zero-inits the atomic accumulators for kernel 2 (no memset node).
// Topology note: two-kernel structure (kernel boundary = free coherence) is
// the measured best (R1=105us, R5=103.5us); fusion variants regressed (R2-R4).
// MAX reduction via DPP (order-free => bit-exact same max); SUM reduction
// kept as the verified __shfl_xor butterfly (summation order preserved).
// ---------------------------------------------------------------------------
__global__ __launch_bounds__(256) void lse_cost_kernel(
    const float* __restrict__ logits, const float* __restrict__ ptime,
    const int* __restrict__ labels, const float* __restrict__ tstamp,
    float* __restrict__ logZ, float* __restrict__ Cg,
    float* __restrict__ lsepart, float* __restrict__ sums, int* __restrict__ counter)
{
    if (blockIdx.x == 0 && threadIdx.x == 0) {
        sums[0] = 0.f; sums[1] = 0.f; *counter = 0;
    }
    const int wave = threadIdx.x >> 6;
    const int lane = threadIdx.x & 63;
    const int bq = blockIdx.x * 4 + wave;          // < 6400
    const int b = bq / QQ, q = bq % QQ;
    const float4* row4 = (const float4*)(logits + (size_t)bq * CC);

    float4 v[8];
    #pragma unroll
    for (int c = 0; c < 8; ++c) v[c] = row4[c * 64 + lane];
    KEEP_ALIVE_V8(v);          // all 8 loads issued + resident (32 VGPRs)

    float m = -INFINITY;
    #pragma unroll
    for (int c = 0; c < 8; ++c)
        m = fmaxf(m, fmaxf(fmaxf(v[c].x, v[c].y), fmaxf(v[c].z, v[c].w)));
    // 64-lane max via DPP (exact: max is order-independent)
    m = dpp_fmax_f32<0xB1>(m);     // quad_perm xor1
    m = dpp_fmax_f32<0x4E>(m);     // quad_perm xor2
    m = dpp_fmax_f32<0x128>(m);    // row_ror:8
    m = dpp_fmax_f32<0x124>(m);    // row_ror:4  -> row max in every lane
    m = dpp_fmax_f32<0x142>(m);    // row_bcast15: rows 1,3 fold rows 0,2
    m = dpp_fmax_f32<0x143>(m);    // row_bcast31: lanes 48-63 hold full max
    m = readlane_f(m, 63);         // SGPR broadcast to all lanes
    KEEP_ALIVE_V8(v);          // keep tile resident across the max reduction

    float sum = 0.f;
    #pragma unroll
    for (int c = 0; c < 8; ++c)
        sum += expf(v[c].x - m) + expf(v[c].y - m) +
               expf(v[c].z - m) + expf(v[c].w - m);
    #pragma unroll
    for (int s = 1; s < 64; s <<= 1) sum += __shfl_xor(sum, s, 64);

    const float lz = m + logf(sum);
    if (lane == 0) logZ[bq] = lz;

    // cost-matrix entries (lanes 0..15: one target each)
    const float pt = ptime[bq];
    if (lane < NN) {
        int lab = labels[b * NN + lane];
        float lg = logits[(size_t)bq * CC + lab];     // L1-hot gather (same row)
        float cc = -expf(lg - lz);
        float ct = fabsf(pt - tstamp[b * NN + lane]);
        float val = cc + TIME_WEIGHT * ct;
        if (isnan(val)) val = 100.0f;
        else if (isinf(val)) val = (val > 0.f) ? 100.0f : -100.0f;
        Cg[((size_t)b * NN + lane) * QQ + q] = val;
    }

    // EOS nll partial: nll0 = logZ - logit[class 0]
    __shared__ float red[4];
    if (lane == 0) red[wave] = lz - logits[(size_t)bq * CC];
    __syncthreads();
    if (threadIdx.x == 0)
        lsepart[blockIdx.x] = red[0] + red[1] + red[2] + red[3];
}

// ---------------------------------------------------------------------------
// Kernel 2: Jonker-Volgenant assignment, one wave per batch. Cost matrix
// staged to LDS as packed float2 (one ds_read_b64 on the critical path,
// 2-way bank alias = free). f64 math operation-identical to numpy _lsa
// (verified absmax 0 in R1-R5). Min-reduction: 4 DPP f64 stages within
// 16-lane rows + 2 DPP row_bcast stages + ONE readlane (was 8 readlanes +
// 3 fmin: the readlane VALU->SALU hazards were ~60-90cy of every pop's
// serial chain). Winning column via equality ballots with cols 1..64
// prioritized == np.argmin lowest-index tie-break.
// Fused tail: CE correction + L1 time partials -> device atomics; last of
// the 64 blocks folds lsepart and writes the final scalar loss.
// ---------------------------------------------------------------------------
__global__ __launch_bounds__(64) void hungarian_kernel(
    const float* __restrict__ Cg, const float* __restrict__ logits,
    const float* __restrict__ ptime, const int* __restrict__ labels,
    const float* __restrict__ tstamp, const float* __restrict__ logZ,
    const float* __restrict__ lsepart, float* __restrict__ sums,
    int* __restrict__ counter, float* __restrict__ out)
{
    const int b = blockIdx.x;
    const int t = threadIdx.x;

    __shared__ float2 costS2[NN][64];
    __shared__ int qsl[NN];

    // Lane t owns columns jc0 = t+1 and (if <=100) jc1 = t+65 (1-based).
    const int jc0 = t + 1;
    const int jc1 = t + 65;
    const bool has2 = (jc1 <= QQ);
    const int t2 = has2 ? (t + 64) : t;            // clamp keeps loads in-bounds

    // stage cost into LDS as packed pairs (plain loads: kernel boundary
    // already made kernel 1's stores globally visible)
    const float* cgb = Cg + (size_t)b * NN * QQ;
    #pragma unroll
    for (int r = 0; r < NN; ++r) {
        float a = cgb[r * QQ + t];
        float c = cgb[r * QQ + t2];
        costS2[r][t] = make_float2(a, c);
    }
    asm volatile("s_waitcnt lgkmcnt(0)" ::: "memory");  // single wave: no barrier

    double v0 = 0.0, v1 = 0.0;          // column potentials (owned)
    double ureg = 0.0;                  // lane r holds u[r+1] (lanes 0..15)
    int preg0 = 0, preg1 = 0;           // p[jc0], p[jc1] (0 = free)
    const double INF = __builtin_inf();

    for (int i = 1; i <= NN; ++i) {
        double minv0 = INF, minv1 = INF;
        bool used0 = false, used1 = false;
        int way0 = 0, way1 = 0;
        bool inTree = (t == i - 1);     // p[0] = i enters the tree at start
        int j0 = 0;
        int i0 = i;                      // p[0]

        while (true) {
            used0 |= (j0 == jc0);
            used1 |= (j0 == jc1);
            inTree = inTree || (t == i0 - 1);
            const double u_i0 = readlane_d(ureg, i0 - 1);

            // wave-uniform row: one ds_read_b64 (2-way bank alias = free)
            const float2 cab = costS2[i0 - 1][t];
            const double ca = (double)cab.x;
            const double cb = (double)cab.y;   // garbage for t>35: never used

            if (!used0) {
                double cur = ca - u_i0 - v0;
                if (cur < minv0) { minv0 = cur; way0 = j0; }
            }
            if (has2 && !used1) {
                double cur = cb - u_i0 - v1;
                if (cur < minv1) { minv1 = cur; way1 = j0; }
            }

            // value-only min reduction, all-DPP: 4 stages within 16-lane
            // rows, 2 row_bcast stages across rows, one readlane broadcast.
            double m0 = used0 ? INF : minv0;
            double m1 = (has2 && !used1) ? minv1 : INF;
            double gmin = fmin(m0, m1);
            gmin = dpp_fmin_f64<0xB1>(gmin);    // quad_perm [1,0,3,2] (xor 1)
            gmin = dpp_fmin_f64<0x4E>(gmin);    // quad_perm [2,3,0,1] (xor 2)
            gmin = dpp_fmin_f64<0x124>(gmin);   // row_ror:4
            gmin = dpp_fmin_f64<0x128>(gmin);   // row_ror:8  -> row min all lanes
            gmin = dpp_fmin_f64<0x142>(gmin);   // row_bcast15: rows 1,3 fold 0,2
            gmin = dpp_fmin_f64<0x143>(gmin);   // row_bcast31: 48-63 full min
            gmin = readlane_d(gmin, 63);        // SGPR broadcast to all lanes
            // winning column: ballot A (cols 1..64) has priority, then B
            unsigned long long A  = __ballot(!used0 && (minv0 == gmin));
            unsigned long long Bm = __ballot(has2 && !used1 && (minv1 == gmin));
            int j1 = (A != 0ull) ? ((int)__builtin_ctzll(A) + 1)
                                 : ((int)__builtin_ctzll(Bm) + 65);
            const double delta = gmin;

            if (inTree) ureg += delta;                   // u[p[used]] += delta
            if (used0) v0 -= delta; else minv0 -= delta;
            if (has2) { if (used1) v1 -= delta; else minv1 -= delta; }

            j0 = j1;
            int pj = (j0 <= 64) ? __builtin_amdgcn_readlane(preg0, j0 - 1)
                                : __builtin_amdgcn_readlane(preg1, j0 - 65);
            if (pj == 0) break;
            i0 = pj;
        }

        // augment along the alternating path (uniform walk)
        while (j0 != 0) {
            int jn = (j0 <= 64) ? __builtin_amdgcn_readlane(way0, j0 - 1)
                                : __builtin_amdgcn_readlane(way1, j0 - 65);
            int pv;
            if (jn == 0) pv = i;
            else pv = (jn <= 64) ? __builtin_amdgcn_readlane(preg0, jn - 1)
                                 : __builtin_amdgcn_readlane(preg1, jn - 65);
            if (j0 == jc0) preg0 = pv;
            if (has2 && j0 == jc1) preg1 = pv;
            j0 = jn;
        }
    }

    // extract matches: qsl[target row] = column (single wave: waitcnt, no bar)
    if (preg0 > 0) qsl[preg0 - 1] = jc0 - 1;
    if (has2 && preg1 > 0) qsl[preg1 - 1] = jc1 - 1;
    asm volatile("s_waitcnt lgkmcnt(0)" ::: "memory");

    // fused tail: CE correction + time-loss partials for this batch
    float corr = 0.f, tl = 0.f;
    if (t < NN) {
        int qcol = qsl[t];
        int lab = labels[b * NN + t];
        int bq = b * QQ + qcol;
        float lz = logZ[bq];
        float lgm = logits[(size_t)bq * CC + lab];
        float lg0 = logits[(size_t)bq * CC];
        corr = (lz - lgm) - EOS_COEF * (lz - lg0);
        tl = fabsf(ptime[bq] - tstamp[b * NN + t]);
    }
    #pragma unroll
    for (int s = 1; s < 64; s <<= 1) {
        corr += __shfl_xor(corr, s, 64);
        tl   += __shfl_xor(tl, s, 64);
    }

    int old = 0;
    if (t == 0) {
        atomicAdd(&sums[0], corr);
        atomicAdd(&sums[1], tl);
        __threadfence();                 // release partials before counter bump
        old = atomicAdd(counter, 1);
    }
    old = __shfl(old, 0, 64);
    if (old == BB - 1) {                 // last block finalizes
        __threadfence();                 // acquire others' partials
        float r0 = 0.f;
        #pragma unroll
        for (int k = 0; k < 25; ++k) r0 += lsepart[t + 64 * k];   // 1600 = 64*25
        #pragma unroll
        for (int s = 1; s < 64; s <<= 1) r0 += __shfl_xor(r0, s, 64);
        if (t == 0) {
            float s0 = atomicAdd(&sums[0], 0.0f);
            float s1 = atomicAdd(&sums[1], 0.0f);
            const float sum_w = (float)(BB * NN) * 1.0f
                              + (float)(BB * (QQ - NN)) * EOS_COEF;   // 1561.6
            float loss_ce = (EOS_COEF * r0 + s0) / sum_w;
            float loss_t  = s1 / (float)(BB * NN);
            out[0] = loss_ce + TIME_WEIGHT * loss_t;
        }
    }
}

// ---------------------------------------------------------------------------
// Workspace layout (bytes):
//   [0,      25600)  : float logZ[6400]
//   [25600, 435200)  : float Cg[64*16*100]
//   [435200, 441600) : float lsepart[1600]
//   [441600, 441608) : float sums[2]   {ce_corr, time}   (zeroed by kernel 1)
//   [441608, 441612) : int   counter                     (zeroed by kernel 1)
// ---------------------------------------------------------------------------
extern "C" void kernel_launch(void* const* d_in, const int* in_sizes, int n_in,
                              void* d_out, int out_size, void* d_ws, size_t ws_size,
                              hipStream_t stream) {
    const float* logits = (const float*)d_in[0];   // [B,Q,2048]
    const float* ptime  = (const float*)d_in[1];   // [B,Q,1]
    const int*   labels = (const int*)d_in[2];     // [B,N]
    const float* tstamp = (const float*)d_in[3];   // [B,N,1]
    float* out = (float*)d_out;

    char* ws = (char*)d_ws;
    float* logZ    = (float*)ws;
    float* Cg      = (float*)(ws + 25600);
    float* lsepart = (float*)(ws + 435200);
    float* sums    = (float*)(ws + 441600);
    int*   counter = (int*)(ws + 441608);

    lse_cost_kernel<<<1600, 256, 0, stream>>>(logits, ptime, labels, tstamp,
                                              logZ, Cg, lsepart, sums, counter);
    hungarian_kernel<<<BB, 64, 0, stream>>>(Cg, logits, ptime, labels, tstamp,
                                            logZ, lsepart, sums, counter, out);
}

// Round 7
// 103.166 us; speedup vs baseline: 1.0289x; 1.0289x over previous
//
#include <hip/hip_runtime.h>
#include <math.h>

// Problem constants
#define BB 64
#define QQ 100
#define NN 16
#define CC 2048            // NUM_CLASSES + 1
#define TIME_WEIGHT 2.0f
#define EOS_COEF 0.1f

__device__ __forceinline__ double readlane_d(double x, int lane) {
    int lo = __builtin_amdgcn_readlane(__double2loint(x), lane);
    int hi = __builtin_amdgcn_readlane(__double2hiint(x), lane);
    return __hiloint2double(hi, lo);
}

// fmin with a DPP-permuted copy of x (both 32-bit halves moved coherently).
// All uses are rotations/permutes within 16-lane rows under full exec.
// NOTE (R6 post-mortem): do NOT extend this chain with row_bcast15/31 f64
// stages -- the serial DPP-f64 chain is SLOWER than 4 independent readlanes
// + fmin tree (readlanes pipeline; DPP stages are dependent). Measured:
// R5 (readlanes) 103.5us vs R6 (row_bcast) 106.1us.
template <int CTRL>
__device__ __forceinline__ double dpp_fmin_f64(double x) {
    int lo_s = __double2loint(x), hi_s = __double2hiint(x);
    int lo = __builtin_amdgcn_update_dpp(lo_s, lo_s, CTRL, 0xF, 0xF, false);
    int hi = __builtin_amdgcn_update_dpp(hi_s, hi_s, CTRL, 0xF, 0xF, false);
    return fmin(x, __hiloint2double(hi, lo));
}

// Keep all 8 float4 row chunks live in VGPRs (32 regs). Without this the
// compiler allocates only 28 VGPRs total (measured R0-R4) and serializes the
// 8 independent dwordx4 loads into a few-in-flight chunked pattern --
// latency-starving the streaming pass. Zero instructions emitted.
#define KEEP_ALIVE_V8(v)                                                     \
    asm volatile("" : "+v"(v[0].x), "+v"(v[0].y), "+v"(v[0].z), "+v"(v[0].w),\
                     "+v"(v[1].x), "+v"(v[1].y), "+v"(v[1].z), "+v"(v[1].w),\
                     "+v"(v[2].x), "+v"(v[2].y), "+v"(v[2].z), "+v"(v[2].w),\
                     "+v"(v[3].x), "+v"(v[3].y), "+v"(v[3].z), "+v"(v[3].w));\
    asm volatile("" : "+v"(v[4].x), "+v"(v[4].y), "+v"(v[4].z), "+v"(v[4].w),\
                     "+v"(v[5].x), "+v"(v[5].y), "+v"(v[5].z), "+v"(v[5].w),\
                     "+v"(v[6].x), "+v"(v[6].y), "+v"(v[6].z), "+v"(v[6].w),\
                     "+v"(v[7].x), "+v"(v[7].y), "+v"(v[7].z), "+v"(v[7].w))

// ---------------------------------------------------------------------------
// Kernel 1: per (b,q) row (one wave each):
//   logZ[b,q] = logsumexp(logits[b,q,:])
//   Cg[b][n][q] = -softmax[label_n] + 2*|pt - ts_n|   (transposed cost matrix)
//   lsepart[block] = sum over 4 rows of (logZ - logit[class 0])   [EOS nll]
// Block 0 zero-inits the atomic accumulators for kernel 2 (no memset node).
// Topology note: two-kernel structure (kernel boundary = free coherence) is
// the measured best (R5=103.5us); all fusion variants regressed (R2-R4);
// DPP reduction rewrites regressed (R6). This is the R5-verified source.
// ---------------------------------------------------------------------------
__global__ __launch_bounds__(256) void lse_cost_kernel(
    const float* __restrict__ logits, const float* __restrict__ ptime,
    const int* __restrict__ labels, const float* __restrict__ tstamp,
    float* __restrict__ logZ, float* __restrict__ Cg,
    float* __restrict__ lsepart, float* __restrict__ sums, int* __restrict__ counter)
{
    if (blockIdx.x == 0 && threadIdx.x == 0) {
        sums[0] = 0.f; sums[1] = 0.f; *counter = 0;
    }
    const int wave = threadIdx.x >> 6;
    const int lane = threadIdx.x & 63;
    const int bq = blockIdx.x * 4 + wave;          // < 6400
    const int b = bq / QQ, q = bq % QQ;
    const float4* row4 = (const float4*)(logits + (size_t)bq * CC);

    float4 v[8];
    #pragma unroll
    for (int c = 0; c < 8; ++c) v[c] = row4[c * 64 + lane];
    KEEP_ALIVE_V8(v);          // all 8 loads issued + resident (32 VGPRs)

    float m = -INFINITY;
    #pragma unroll
    for (int c = 0; c < 8; ++c)
        m = fmaxf(m, fmaxf(fmaxf(v[c].x, v[c].y), fmaxf(v[c].z, v[c].w)));
    #pragma unroll
    for (int s = 1; s < 64; s <<= 1) m = fmaxf(m, __shfl_xor(m, s, 64));
    KEEP_ALIVE_V8(v);          // keep tile resident across the max reduction

    float sum = 0.f;
    #pragma unroll
    for (int c = 0; c < 8; ++c)
        sum += expf(v[c].x - m) + expf(v[c].y - m) +
               expf(v[c].z - m) + expf(v[c].w - m);
    #pragma unroll
    for (int s = 1; s < 64; s <<= 1) sum += __shfl_xor(sum, s, 64);

    const float lz = m + logf(sum);
    if (lane == 0) logZ[bq] = lz;

    // cost-matrix entries (lanes 0..15: one target each)
    const float pt = ptime[bq];
    if (lane < NN) {
        int lab = labels[b * NN + lane];
        float lg = logits[(size_t)bq * CC + lab];     // L1-hot gather (same row)
        float cc = -expf(lg - lz);
        float ct = fabsf(pt - tstamp[b * NN + lane]);
        float val = cc + TIME_WEIGHT * ct;
        if (isnan(val)) val = 100.0f;
        else if (isinf(val)) val = (val > 0.f) ? 100.0f : -100.0f;
        Cg[((size_t)b * NN + lane) * QQ + q] = val;
    }

    // EOS nll partial: nll0 = logZ - logit[class 0]
    __shared__ float red[4];
    if (lane == 0) red[wave] = lz - logits[(size_t)bq * CC];
    __syncthreads();
    if (threadIdx.x == 0)
        lsepart[blockIdx.x] = red[0] + red[1] + red[2] + red[3];
}

// ---------------------------------------------------------------------------
// Kernel 2: Jonker-Volgenant assignment, one wave per batch. Cost matrix
// staged to LDS as packed float2 (one ds_read_b64 on the critical path,
// 2-way bank alias = free). f64 math operation-identical to numpy _lsa
// (verified absmax 0 in R1-R6). Min-reduction: 4 DPP f64 stages within
// 16-lane rows + 4 INDEPENDENT readlanes + 3 fmin (faster than the serial
// row_bcast DPP chain -- see R6 note above). Winning column via equality
// ballots with cols 1..64 prioritized == np.argmin lowest-index tie-break.
// Fused tail: CE correction + L1 time partials -> device atomics; last of
// the 64 blocks folds lsepart and writes the final scalar loss.
// ---------------------------------------------------------------------------
__global__ __launch_bounds__(64) void hungarian_kernel(
    const float* __restrict__ Cg, const float* __restrict__ logits,
    const float* __restrict__ ptime, const int* __restrict__ labels,
    const float* __restrict__ tstamp, const float* __restrict__ logZ,
    const float* __restrict__ lsepart, float* __restrict__ sums,
    int* __restrict__ counter, float* __restrict__ out)
{
    const int b = blockIdx.x;
    const int t = threadIdx.x;

    __shared__ float2 costS2[NN][64];
    __shared__ int qsl[NN];

    // Lane t owns columns jc0 = t+1 and (if <=100) jc1 = t+65 (1-based).
    const int jc0 = t + 1;
    const int jc1 = t + 65;
    const bool has2 = (jc1 <= QQ);
    const int t2 = has2 ? (t + 64) : t;            // clamp keeps loads in-bounds

    // stage cost into LDS as packed pairs (plain loads: kernel boundary
    // already made kernel 1's stores globally visible)
    const float* cgb = Cg + (size_t)b * NN * QQ;
    #pragma unroll
    for (int r = 0; r < NN; ++r) {
        float a = cgb[r * QQ + t];
        float c = cgb[r * QQ + t2];
        costS2[r][t] = make_float2(a, c);
    }
    asm volatile("s_waitcnt lgkmcnt(0)" ::: "memory");  // single wave: no barrier

    double v0 = 0.0, v1 = 0.0;          // column potentials (owned)
    double ureg = 0.0;                  // lane r holds u[r+1] (lanes 0..15)
    int preg0 = 0, preg1 = 0;           // p[jc0], p[jc1] (0 = free)
    const double INF = __builtin_inf();

    for (int i = 1; i <= NN; ++i) {
        double minv0 = INF, minv1 = INF;
        bool used0 = false, used1 = false;
        int way0 = 0, way1 = 0;
        bool inTree = (t == i - 1);     // p[0] = i enters the tree at start
        int j0 = 0;
        int i0 = i;                      // p[0]

        while (true) {
            used0 |= (j0 == jc0);
            used1 |= (j0 == jc1);
            inTree = inTree || (t == i0 - 1);
            const double u_i0 = readlane_d(ureg, i0 - 1);

            // wave-uniform row: one ds_read_b64 (2-way bank alias = free)
            const float2 cab = costS2[i0 - 1][t];
            const double ca = (double)cab.x;
            const double cb = (double)cab.y;   // garbage for t>35: never used

            if (!used0) {
                double cur = ca - u_i0 - v0;
                if (cur < minv0) { minv0 = cur; way0 = j0; }
            }
            if (has2 && !used1) {
                double cur = cb - u_i0 - v1;
                if (cur < minv1) { minv1 = cur; way1 = j0; }
            }

            // value-only min reduction: 4 DPP stages within 16-lane rows,
            // then 4 independent readlanes + 3 fmin across rows.
            double m0 = used0 ? INF : minv0;
            double m1 = (has2 && !used1) ? minv1 : INF;
            double gmin = fmin(m0, m1);
            gmin = dpp_fmin_f64<0xB1>(gmin);    // quad_perm [1,0,3,2] (xor 1)
            gmin = dpp_fmin_f64<0x4E>(gmin);    // quad_perm [2,3,0,1] (xor 2)
            gmin = dpp_fmin_f64<0x124>(gmin);   // row_ror:4
            gmin = dpp_fmin_f64<0x128>(gmin);   // row_ror:8
            {
                double h0 = readlane_d(gmin, 0);
                double h1 = readlane_d(gmin, 16);
                double h2 = readlane_d(gmin, 32);
                double h3 = readlane_d(gmin, 48);
                gmin = fmin(fmin(h0, h1), fmin(h2, h3));
            }
            // winning column: ballot A (cols 1..64) has priority, then B
            unsigned long long A  = __ballot(!used0 && (minv0 == gmin));
            unsigned long long Bm = __ballot(has2 && !used1 && (minv1 == gmin));
            int j1 = (A != 0ull) ? ((int)__builtin_ctzll(A) + 1)
                                 : ((int)__builtin_ctzll(Bm) + 65);
            const double delta = gmin;

            if (inTree) ureg += delta;                   // u[p[used]] += delta
            if (used0) v0 -= delta; else minv0 -= delta;
            if (has2) { if (used1) v1 -= delta; else minv1 -= delta; }

            j0 = j1;
            int pj = (j0 <= 64) ? __builtin_amdgcn_readlane(preg0, j0 - 1)
                                : __builtin_amdgcn_readlane(preg1, j0 - 65);
            if (pj == 0) break;
            i0 = pj;
        }

        // augment along the alternating path (uniform walk)
        while (j0 != 0) {
            int jn = (j0 <= 64) ? __builtin_amdgcn_readlane(way0, j0 - 1)
                                : __builtin_amdgcn_readlane(way1, j0 - 65);
            int pv;
            if (jn == 0) pv = i;
            else pv = (jn <= 64) ? __builtin_amdgcn_readlane(preg0, jn - 1)
                                 : __builtin_amdgcn_readlane(preg1, jn - 65);
            if (j0 == jc0) preg0 = pv;
            if (has2 && j0 == jc1) preg1 = pv;
            j0 = jn;
        }
    }

    // extract matches: qsl[target row] = column (single wave: waitcnt, no bar)
    if (preg0 > 0) qsl[preg0 - 1] = jc0 - 1;
    if (has2 && preg1 > 0) qsl[preg1 - 1] = jc1 - 1;
    asm volatile("s_waitcnt lgkmcnt(0)" ::: "memory");

    // fused tail: CE correction + time-loss partials for this batch
    float corr = 0.f, tl = 0.f;
    if (t < NN) {
        int qcol = qsl[t];
        int lab = labels[b * NN + t];
        int bq = b * QQ + qcol;
        float lz = logZ[bq];
        float lgm = logits[(size_t)bq * CC + lab];
        float lg0 = logits[(size_t)bq * CC];
        corr = (lz - lgm) - EOS_COEF * (lz - lg0);
        tl = fabsf(ptime[bq] - tstamp[b * NN + t]);
    }
    #pragma unroll
    for (int s = 1; s < 64; s <<= 1) {
        corr += __shfl_xor(corr, s, 64);
        tl   += __shfl_xor(tl, s, 64);
    }

    int old = 0;
    if (t == 0) {
        atomicAdd(&sums[0], corr);
        atomicAdd(&sums[1], tl);
        __threadfence();                 // release partials before counter bump
        old = atomicAdd(counter, 1);
    }
    old = __shfl(old, 0, 64);
    if (old == BB - 1) {                 // last block finalizes
        __threadfence();                 // acquire others' partials
        float r0 = 0.f;
        #pragma unroll
        for (int k = 0; k < 25; ++k) r0 += lsepart[t + 64 * k];   // 1600 = 64*25
        #pragma unroll
        for (int s = 1; s < 64; s <<= 1) r0 += __shfl_xor(r0, s, 64);
        if (t == 0) {
            float s0 = atomicAdd(&sums[0], 0.0f);
            float s1 = atomicAdd(&sums[1], 0.0f);
            const float sum_w = (float)(BB * NN) * 1.0f
                              + (float)(BB * (QQ - NN)) * EOS_COEF;   // 1561.6
            float loss_ce = (EOS_COEF * r0 + s0) / sum_w;
            float loss_t  = s1 / (float)(BB * NN);
            out[0] = loss_ce + TIME_WEIGHT * loss_t;
        }
    }
}

// ---------------------------------------------------------------------------
// Workspace layout (bytes):
//   [0,      25600)  : float logZ[6400]
//   [25600, 435200)  : float Cg[64*16*100]
//   [435200, 441600) : float lsepart[1600]
//   [441600, 441608) : float sums[2]   {ce_corr, time}   (zeroed by kernel 1)
//   [441608, 441612) : int   counter                     (zeroed by kernel 1)
// ---------------------------------------------------------------------------
extern "C" void kernel_launch(void* const* d_in, const int* in_sizes, int n_in,
                              void* d_out, int out_size, void* d_ws, size_t ws_size,
                              hipStream_t stream) {
    const float* logits = (const float*)d_in[0];   // [B,Q,2048]
    const float* ptime  = (const float*)d_in[1];   // [B,Q,1]
    const int*   labels = (const int*)d_in[2];     // [B,N]
    const float* tstamp = (const float*)d_in[3];   // [B,N,1]
    float* out = (float*)d_out;

    char* ws = (char*)d_ws;
    float* logZ    = (float*)ws;
    float* Cg      = (float*)(ws + 25600);
    float* lsepart = (float*)(ws + 435200);
    float* sums    = (float*)(ws + 441600);
    int*   counter = (int*)(ws + 441608);

    lse_cost_kernel<<<1600, 256, 0, stream>>>(logits, ptime, labels, tstamp,
                                              logZ, Cg, lsepart, sums, counter);
    hungarian_kernel<<<BB, 64, 0, stream>>>(Cg, logits, ptime, labels, tstamp,
                                            logZ, lsepart, sums, counter, out);
}